// Round 19
// baseline (92.703 us; speedup 1.0000x reference)
//
#include <hip/hip_runtime.h>
#include <hip/hip_bf16.h>

// B=4, S=2048, D=512, H=8, DH=64
// GEMMs: m97-structure 128x128 LDS-staged (GLDS w16 + XOR swizzle), bf16 A+B
// (measured-best core from round 17).
// flash v12 = v11 + complementary-pair dispatch order: per XCD, first 32 blocks
// p=15..8, next 32 p=0..7 -> slot-paired blocks sum to uniform 25 iters/CU.
// v11: XCD-aware mapping (FETCH 66->13MB), KVBLK=128/barrier, flat softmax via
// raw v_exp_f32 (tril zeros pin max~0), masked tail via V suffix sums.

typedef __bf16 bf16;
typedef __bf16 bf16x8 __attribute__((ext_vector_type(8)));
typedef __bf16 bf16x4v __attribute__((ext_vector_type(4)));
typedef float f32x4 __attribute__((ext_vector_type(4)));

#define S_LEN 2048
#define DMODEL 512
// log2(e)/sqrt(512): Q pre-scale so softmax exp is a bare exp2
#define QSCALE 0.06375870914f

#define GLDS(g, l) __builtin_amdgcn_global_load_lds(                  \
    (const __attribute__((address_space(1))) void*)(g),               \
    (__attribute__((address_space(3))) void*)(l), 16, 0, 0)

#define EXP2(x) __builtin_amdgcn_exp2f(x)

// One launch: embed (1,048,576 f4) then Wq,Wk,Wv,Wo (65,536 f4 each).
__global__ __launch_bounds__(256) void cast_all(
    const float* __restrict__ embed, const float* __restrict__ Wq,
    const float* __restrict__ Wk, const float* __restrict__ Wv,
    const float* __restrict__ Wo,
    bf16* __restrict__ Eb, bf16* __restrict__ Wqkv, bf16* __restrict__ Wob) {
  int i = blockIdx.x * 256 + threadIdx.x;
  const float* src;
  bf16* dst;
  int il;
  if (i < 1048576) {
    src = embed; dst = Eb; il = i;
  } else {
    int j = i - 1048576;
    int w = j >> 16;
    il = j & 65535;
    src = (w == 0) ? Wq : (w == 1) ? Wk : (w == 2) ? Wv : Wo;
    dst = (w == 3) ? Wob : Wqkv + (size_t)w * 262144;
  }
  float4 v = reinterpret_cast<const float4*>(src)[il];
  bf16x4v o;
  o[0] = (bf16)v.x; o[1] = (bf16)v.y; o[2] = (bf16)v.z; o[3] = (bf16)v.w;
  *reinterpret_cast<bf16x4v*>(dst + (size_t)il * 4) = o;
}

// ---- 128x128 tile GEMM core: C = A[M,512] * Bw[N,512]^T, K=512, BK=64 ----
__device__ __forceinline__ void gemm128_core(
    const bf16* __restrict__ A, const bf16* __restrict__ Bw,
    int row0, int col0, bf16* As, bf16* Bs, f32x4 (&acc)[4][4]) {
  int tid = threadIdx.x;
  int w = tid >> 6, l = tid & 63, lr = l & 15, lg = l >> 4;
  int wr = w >> 1, wc = w & 1;

  int srow = w * 8 + (l >> 3);
  int scol = ((l & 7) ^ (srow & 7)) << 3;
  const bf16* ga = A + (size_t)(row0 + srow) * DMODEL + scol;
  const bf16* gb = Bw + (size_t)(col0 + srow) * DMODEL + scol;
  char* asb = (char*)As;
  char* bsb = (char*)Bs;
  int sbase = w * 1024;

  int aoff[4], boff[4];
#pragma unroll
  for (int m = 0; m < 4; ++m) {
    aoff[m] = (wr * 64 + m * 16 + lr) * 128 + (((lg ^ (lr & 7))) << 4);
    boff[m] = (wc * 64 + m * 16 + lr) * 128 + (((lg ^ (lr & 7))) << 4);
  }

  for (int k0 = 0; k0 < DMODEL; k0 += 64) {
#pragma unroll
    for (int qt = 0; qt < 4; ++qt) {
      GLDS(ga + (size_t)qt * 32 * DMODEL, asb + qt * 4096 + sbase);
      GLDS(gb + (size_t)qt * 32 * DMODEL, bsb + qt * 4096 + sbase);
    }
    ga += 64; gb += 64;
    __syncthreads();

    bf16x8 af[2][4], bfv[2][4];
#pragma unroll
    for (int m = 0; m < 4; ++m) {
      af[0][m] = *(const bf16x8*)(asb + aoff[m]);
      af[1][m] = *(const bf16x8*)(asb + (aoff[m] ^ 0x40));
      bfv[0][m] = *(const bf16x8*)(bsb + boff[m]);
      bfv[1][m] = *(const bf16x8*)(bsb + (boff[m] ^ 0x40));
    }
#pragma unroll
    for (int m = 0; m < 4; ++m)
#pragma unroll
      for (int n = 0; n < 4; ++n) {
        acc[m][n] = __builtin_amdgcn_mfma_f32_16x16x32_bf16(af[0][m], bfv[0][n], acc[m][n], 0, 0, 0);
        acc[m][n] = __builtin_amdgcn_mfma_f32_16x16x32_bf16(af[1][m], bfv[1][n], acc[m][n], 0, 0, 0);
      }
    __syncthreads();
  }
}

// Fused QKV GEMM: Wqkv[1536][512]; col-tiles 0-3 = Q, 4-7 = K, 8-11 = V.
__global__ __launch_bounds__(256) void gemm_qkv(
    const bf16* __restrict__ A, const bf16* __restrict__ Wqkv,
    const float* __restrict__ bq, const float* __restrict__ bk, const float* __restrict__ bv,
    bf16* __restrict__ Qb, bf16* __restrict__ Kb, bf16* __restrict__ Vt) {
  __shared__ __align__(16) bf16 As[128 * 64];
  __shared__ __align__(16) bf16 Bs[128 * 64];
  int row0 = blockIdx.x * 128, col0 = blockIdx.y * 128;
  f32x4 acc[4][4] = {};
  gemm128_core(A, Wqkv, row0, col0, As, Bs, acc);

  int tid = threadIdx.x;
  int w = tid >> 6, l = tid & 63, lr = l & 15, lg = l >> 4;
  int wr = w >> 1, wc = w & 1;
  int z2 = col0 >> 9;  // 0=Q 1=K 2=V (uniform per block)
  if (z2 < 2) {
    bf16* O = z2 ? Kb : Qb;
    const float* bias = z2 ? bk : bq;
    float qs = z2 ? 1.0f : QSCALE;
#pragma unroll
    for (int n = 0; n < 4; ++n) {
      int cg = (col0 & 511) + wc * 64 + n * 16 + lr;
      float bi = bias[cg];
#pragma unroll
      for (int m = 0; m < 4; ++m) {
        int rg = row0 + wr * 64 + m * 16 + lg * 4;
#pragma unroll
        for (int r = 0; r < 4; ++r)
          O[(size_t)(rg + r) * DMODEL + cg] = (bf16)((acc[m][n][r] + bi) * qs);
      }
    }
  } else {
    // V: store transposed Vt[b][h][e][s]
#pragma unroll
    for (int n = 0; n < 4; ++n) {
      int ep = (col0 & 511) + wc * 64 + n * 16 + lr;
      int h = ep >> 6, e = ep & 63;
      float bi = bv[ep];
#pragma unroll
      for (int m = 0; m < 4; ++m) {
        int rg = row0 + wr * 64 + m * 16 + lg * 4;
        int b = rg >> 11, s0 = rg & 2047;
        bf16x4v pk;
#pragma unroll
        for (int r = 0; r < 4; ++r) pk[r] = (bf16)(acc[m][n][r] + bi);
        *(bf16x4v*)(Vt + ((size_t)((b * 8 + h) * 64 + e)) * S_LEN + s0) = pk;
      }
    }
  }
}

// Wo GEMM + bias + residual, bf16 out (LN reads bf16).
__global__ __launch_bounds__(256) void gemm_wo(
    const bf16* __restrict__ A, const bf16* __restrict__ W,
    const float* __restrict__ bo, const float* __restrict__ embed,
    bf16* __restrict__ X) {
  __shared__ __align__(16) bf16 As[128 * 64];
  __shared__ __align__(16) bf16 Bs[128 * 64];
  int row0 = blockIdx.x * 128, col0 = blockIdx.y * 128;
  f32x4 acc[4][4] = {};
  gemm128_core(A, W, row0, col0, As, Bs, acc);

  int tid = threadIdx.x;
  int w = tid >> 6, l = tid & 63, lr = l & 15, lg = l >> 4;
  int wr = w >> 1, wc = w & 1;
#pragma unroll
  for (int n = 0; n < 4; ++n) {
    int cg = col0 + wc * 64 + n * 16 + lr;
    float bi = bo[cg];
#pragma unroll
    for (int m = 0; m < 4; ++m) {
      int rg = row0 + wr * 64 + m * 16 + lg * 4;
#pragma unroll
      for (int r = 0; r < 4; ++r)
        X[(size_t)(rg + r) * DMODEL + cg] =
            (bf16)(acc[m][n][r] + bi + embed[(size_t)(rg + r) * DMODEL + cg]);
    }
  }
}

// SUF[bh][j][e] = sum_{t >= 16j} V[t][e], j = 0..128 (SUF[128]=0).
// 256 blocks: (bh, e-group of 8); 256 thr = (el 0..7, seg 0..31), 4 chunks/seg.
__global__ __launch_bounds__(256) void suf_kernel(const bf16* __restrict__ Vt,
                                                  float* __restrict__ SUF) {
  int bh = blockIdx.x >> 3;
  int eg = blockIdx.x & 7;
  int el = threadIdx.x & 7;
  int seg = threadIdx.x >> 3;  // 0..31
  int e = eg * 8 + el;
  __shared__ float segtot[32][9];
  const bf16* vrow = Vt + ((size_t)bh * 64 + e) * S_LEN;
  float loc[4];
  float carry = 0.f;
#pragma unroll
  for (int j = 3; j >= 0; --j) {
    int jj = seg * 4 + j;
    bf16x8 a = *(const bf16x8*)(vrow + jj * 16);
    bf16x8 b2 = *(const bf16x8*)(vrow + jj * 16 + 8);
    float s = 0.f;
#pragma unroll
    for (int k = 0; k < 8; ++k) s += (float)a[k] + (float)b2[k];
    carry += s;
    loc[j] = carry;
  }
  segtot[seg][el] = carry;
  __syncthreads();
  float add = 0.f;
  for (int s2 = seg + 1; s2 < 32; ++s2) add += segtot[s2][el];
  float* srow = SUF + (size_t)bh * 129 * 64 + e;
#pragma unroll
  for (int j = 0; j < 4; ++j) srow[(size_t)(seg * 4 + j) * 64] = loc[j] + add;
  if (seg == 0) srow[(size_t)128 * 64] = 0.f;
}

// Flash attention v12: XCD-aware 1D grid (512 blocks); per XCD the 64 blocks
// launch as p=15..8 (4 bh each) then p=0..7, so slot-paired blocks sum to a
// uniform 25 iterations per CU. 8 waves: 0-3 big tile (16+p), 4-7 small (15-p);
// KVBLK=128 per barrier, two wave-local phases; flat softmax via raw v_exp_f32.
__global__ __launch_bounds__(512) void flash_attn(
    const bf16* __restrict__ Qb, const bf16* __restrict__ Kb,
    const bf16* __restrict__ Vt, const float* __restrict__ SUF,
    bf16* __restrict__ attO) {
  int id = blockIdx.x;           // 0..511
  int g = id & 7;                // XCD (dispatch round-robins id%8)
  int j = id >> 3;               // 0..63 within XCD
  int bh = g * 4 + (j & 3);      // 4 bh per XCD
  int p = (j < 32) ? (15 - (j >> 2)) : ((j - 32) >> 2);  // complementary pairing
  int b = bh >> 3, h = bh & 7;
  int tid = threadIdx.x;
  int w = tid >> 6, l = tid & 63, lr = l & 15, lg = l >> 4;
  int wsub = w & 3;
  int qtile = (w < 4) ? (16 + p) : (15 - p);
  int qb = qtile * 64;
  int qbw = qb + 16 * wsub;          // first q-row of this wave's strip
  int tmax_w = qbw + 16;             // analytic tail starts here
  int nt = (18 + p) >> 1;            // block-uniform 128-wide KV tiles
  int ntw = (tmax_w + 127) >> 7;     // this wave's active iterations

  __shared__ __align__(16) bf16 kl[2][128 * 64];    // K tile [t][e], swizzled
  __shared__ __align__(16) bf16 vl[2][2][64 * 64];  // V^T subtiles [e][t], swizzled
  __shared__ __align__(16) bf16 pl[8][16 * 64];     // per-wave P tile [s][t], swizzled

  const bf16* qptr = Qb + ((size_t)(b * S_LEN) + qbw + lr) * DMODEL + h * 64 + lg * 8;
  bf16x8 aq0 = *(const bf16x8*)(qptr);
  bf16x8 aq1 = *(const bf16x8*)(qptr + 32);

  float lsum[4] = {0.f, 0.f, 0.f, 0.f};
  f32x4 acc[4] = {};

  int grow = tid >> 3, gch = tid & 7;
  int sch = ((gch ^ (grow & 7)) << 3);   // (grow+64)&7 == grow&7
  const bf16* Kg = Kb + ((size_t)(b * S_LEN) + grow) * DMODEL + h * 64 + sch;
  const bf16* Vg = Vt + ((size_t)(bh * 64) + grow) * S_LEN + sch;
  int sdst = w * 1024;  // wave-uniform LDS dest (lane*16 implicit)

  int sw0 = (lg ^ (lr & 7)) << 4;
  int sw4 = sw0 ^ 0x40;
  char* plb = (char*)pl[w];

  // prologue: stage tile 0 (K rows 0-63, 64-127; V subtiles 0,1)
  GLDS(Kg, (char*)kl[0] + sdst);
  GLDS(Kg + (size_t)64 * DMODEL, (char*)kl[0] + 8192 + sdst);
  GLDS(Vg, (char*)vl[0][0] + sdst);
  GLDS(Vg + 64, (char*)vl[0][1] + sdst);
  asm volatile("s_waitcnt vmcnt(0)" ::: "memory");
  __syncthreads();

  int cur = 0;
  for (int it = 0; it < nt; ++it) {
    int t0 = it << 7;
    if (it + 1 < nt) {
      GLDS(Kg + (size_t)(t0 + 128) * DMODEL, (char*)kl[cur ^ 1] + sdst);
      GLDS(Kg + (size_t)(t0 + 192) * DMODEL, (char*)kl[cur ^ 1] + 8192 + sdst);
      GLDS(Vg + (t0 + 128), (char*)vl[cur ^ 1][0] + sdst);
      GLDS(Vg + (t0 + 192), (char*)vl[cur ^ 1][1] + sdst);
    }
    if (it < ntw) {  // wave-uniform skip of fully-masked tiles
      char* klb = (char*)kl[cur];
      bool ph1 = (t0 + 64) < tmax_w;  // wave-uniform

      // QK^T over the 128-t tile (sf[c] covers t = t0+16c+lr)
      f32x4 sf[8];
      const f32x4 fz = {0.f, 0.f, 0.f, 0.f};
      int ncq = ph1 ? 8 : 4;
      __builtin_amdgcn_s_setprio(1);
#pragma unroll 8
      for (int c = 0; c < 8; ++c) {
        if (c < ncq) {
          int rb = (16 * c + lr) * 128;
          bf16x8 bk0 = *(const bf16x8*)(klb + rb + sw0);
          bf16x8 bk1 = *(const bf16x8*)(klb + rb + sw4);
          f32x4 t = __builtin_amdgcn_mfma_f32_16x16x32_bf16(aq0, bk0, fz, 0, 0, 0);
          sf[c] = __builtin_amdgcn_mfma_f32_16x16x32_bf16(aq1, bk1, t, 0, 0, 0);
        }
      }
      __builtin_amdgcn_s_setprio(0);

      // two phases: softmax (c-half) -> P tile -> PV with V subtile
#pragma unroll
      for (int hp = 0; hp < 2; ++hp) {
        int t0p = t0 + 64 * hp;
        if (hp == 1 && !ph1) break;
        char* vlb = (char*)vl[cur][hp];

        if (t0p + 64 <= qbw) {
          // interior: no masking
#pragma unroll
          for (int r = 0; r < 4; ++r) {
            int row = lg * 4 + r;
            int pbase = row * 128 + ((lr & 7) << 1);
            int xorv = row & 7;
            float psum = 0.f;
#pragma unroll
            for (int c = 0; c < 4; ++c) {
              float pv = EXP2(sf[4 * hp + c][r]);
              psum += pv;
              int chunk = 2 * c + (lr >> 3);
              *(bf16*)(plb + pbase + (((chunk ^ xorv) << 4))) = (bf16)pv;
            }
            lsum[r] += psum;
          }
        } else {
          // boundary: per-element mask (x=0 in tril-zero region, -inf past tail)
#pragma unroll
          for (int r = 0; r < 4; ++r) {
            int sg = qbw + lg * 4 + r;
            int row = lg * 4 + r;
            int pbase = row * 128 + ((lr & 7) << 1);
            int xorv = row & 7;
            float psum = 0.f;
#pragma unroll
            for (int c = 0; c < 4; ++c) {
              int tg = t0p + 16 * c + lr;
              float x = (tg <= sg) ? sf[4 * hp + c][r] : ((tg < tmax_w) ? 0.f : -1e30f);
              float pv = EXP2(x);
              psum += pv;
              int chunk = 2 * c + (lr >> 3);
              *(bf16*)(plb + pbase + (((chunk ^ xorv) << 4))) = (bf16)pv;
            }
            lsum[r] += psum;
          }
        }

        bf16x8 pa0 = *(const bf16x8*)(plb + lr * 128 + sw0);
        bf16x8 pa1 = *(const bf16x8*)(plb + lr * 128 + sw4);
        __builtin_amdgcn_s_setprio(1);
#pragma unroll
        for (int c = 0; c < 4; ++c) {
          int rb = (16 * c + lr) * 128;
          bf16x8 bv0 = *(const bf16x8*)(vlb + rb + sw0);
          bf16x8 bv1 = *(const bf16x8*)(vlb + rb + sw4);
          acc[c] = __builtin_amdgcn_mfma_f32_16x16x32_bf16(pa0, bv0, acc[c], 0, 0, 0);
          acc[c] = __builtin_amdgcn_mfma_f32_16x16x32_bf16(pa1, bv1, acc[c], 0, 0, 0);
        }
        __builtin_amdgcn_s_setprio(0);
      }
    }
    asm volatile("s_waitcnt vmcnt(0)" ::: "memory");
    __syncthreads();
    cur ^= 1;
  }

#pragma unroll
  for (int r = 0; r < 4; ++r) {
#pragma unroll
    for (int d = 1; d < 16; d <<= 1) lsum[r] += __shfl_xor(lsum[r], d, 64);
  }

  int j16 = tmax_w >> 4;
  const float* suf = SUF + ((size_t)bh * 129 + j16) * 64;
  float cnt = (float)(S_LEN - tmax_w);
  float sufe[4];
#pragma unroll
  for (int c = 0; c < 4; ++c) sufe[c] = suf[16 * c + lr];
#pragma unroll
  for (int r = 0; r < 4; ++r) {
    float inv = 1.f / (lsum[r] + cnt);
    int sg = qbw + lg * 4 + r;
#pragma unroll
    for (int c = 0; c < 4; ++c) {
      float o = (acc[c][r] + sufe[c]) * inv;
      attO[((size_t)(b * S_LEN) + sg) * DMODEL + h * 64 + 16 * c + lr] = (bf16)o;
    }
  }
}

__global__ __launch_bounds__(256) void ln_kernel(const bf16* __restrict__ x,
                                                 const float* __restrict__ gamma,
                                                 const float* __restrict__ beta,
                                                 float* __restrict__ out) {
  int row = blockIdx.x * 4 + (threadIdx.x >> 6);
  int l = threadIdx.x & 63;
  bf16x8 xv = *(const bf16x8*)(x + (size_t)row * DMODEL + l * 8);
  float xf[8];
  float s = 0.f, s2 = 0.f;
#pragma unroll
  for (int k = 0; k < 8; ++k) {
    xf[k] = (float)xv[k];
    s += xf[k];
    s2 += xf[k] * xf[k];
  }
#pragma unroll
  for (int d = 1; d < 64; d <<= 1) {
    s += __shfl_xor(s, d, 64);
    s2 += __shfl_xor(s2, d, 64);
  }
  float mean = s * (1.f / 512.f);
  float var = s2 * (1.f / 512.f) - mean * mean;
  float rstd = rsqrtf(var + 1e-5f);
  const float4* g4 = reinterpret_cast<const float4*>(gamma) + l * 2;
  const float4* b4 = reinterpret_cast<const float4*>(beta) + l * 2;
  float4 g0 = g4[0], g1 = g4[1], bb0 = b4[0], bb1 = b4[1];
  float4 o0, o1;
  o0.x = (xf[0] - mean) * rstd * g0.x + bb0.x;
  o0.y = (xf[1] - mean) * rstd * g0.y + bb0.y;
  o0.z = (xf[2] - mean) * rstd * g0.z + bb0.z;
  o0.w = (xf[3] - mean) * rstd * g0.w + bb0.w;
  o1.x = (xf[4] - mean) * rstd * g1.x + bb1.x;
  o1.y = (xf[5] - mean) * rstd * g1.y + bb1.y;
  o1.z = (xf[6] - mean) * rstd * g1.z + bb1.z;
  o1.w = (xf[7] - mean) * rstd * g1.w + bb1.w;
  float4* orow = reinterpret_cast<float4*>(out + (size_t)row * DMODEL) + l * 2;
  orow[0] = o0;
  orow[1] = o1;
}

extern "C" void kernel_launch(void* const* d_in, const int* in_sizes, int n_in,
                              void* d_out, int out_size, void* d_ws, size_t ws_size,
                              hipStream_t stream) {
  const float* embed = (const float*)d_in[0];
  const float* Wq = (const float*)d_in[1];
  const float* bq = (const float*)d_in[2];
  const float* Wk = (const float*)d_in[3];
  const float* bk = (const float*)d_in[4];
  const float* Wv = (const float*)d_in[5];
  const float* bv = (const float*)d_in[6];
  const float* Wo = (const float*)d_in[7];
  const float* bo = (const float*)d_in[8];
  const float* gamma = (const float*)d_in[9];
  const float* beta = (const float*)d_in[10];
  float* out = (float*)d_out;

  char* ws = (char*)d_ws;
  size_t off = 0;
  auto alc = [&](size_t b) { size_t o = off; off += (b + 255) & ~(size_t)255; return o; };
  bf16* Eb    = (bf16*)(ws + alc(8192ull * 512 * 2));
  bf16* Wqkv  = (bf16*)(ws + alc(1536ull * 512 * 2));
  bf16* Wob   = (bf16*)(ws + alc(512ull * 512 * 2));
  bf16* Qb    = (bf16*)(ws + alc(8192ull * 512 * 2));
  bf16* Kb    = (bf16*)(ws + alc(8192ull * 512 * 2));
  bf16* Vt    = (bf16*)(ws + alc(8192ull * 512 * 2));
  float* SUF  = (float*)(ws + alc(32ull * 129 * 64 * 4));
  bf16* AttO  = (bf16*)(ws + alc(8192ull * 512 * 2));
  bf16* Xb    = (bf16*)(ws + alc(8192ull * 512 * 2));
  (void)ws_size; (void)n_in; (void)in_sizes; (void)out_size;

  cast_all<<<5120, 256, 0, stream>>>(embed, Wq, Wk, Wv, Wo, Eb, Wqkv, Wob);

  gemm_qkv<<<dim3(64, 12), 256, 0, stream>>>(Eb, Wqkv, bq, bk, bv, Qb, Kb, Vt);
  suf_kernel<<<256, 256, 0, stream>>>(Vt, SUF);
  flash_attn<<<512, 512, 0, stream>>>(Qb, Kb, Vt, SUF, AttO);
  gemm_wo<<<dim3(64, 4), 256, 0, stream>>>(AttO, Wob, bo, embed, Xb);
  ln_kernel<<<2048, 256, 0, stream>>>(Xb, gamma, beta, out);
}

// Round 20
// 91.880 us; speedup vs baseline: 1.0090x; 1.0090x over previous
//
#include <hip/hip_runtime.h>
#include <hip/hip_bf16.h>

// B=4, S=2048, D=512, H=8, DH=64  — FINAL (best-measured config, 92.2 us)
// GEMMs: m97-structure 128x128 LDS-staged (GLDS w16 + XOR swizzle), bf16 A+B.
// flash v11: XCD-aware mapping (each XCD owns 4 bh -> K/V L2-local; FETCH
// 66->13MB), KVBLK=128 per barrier, K [128t][64e], V 2x[64e][64t], per-wave P
// [16][64] reused across 2 wave-local phases, flat softmax via raw v_exp_f32
// (tril zeros pin max~0 -> no online max), masked tail via V suffix sums.

typedef __bf16 bf16;
typedef __bf16 bf16x8 __attribute__((ext_vector_type(8)));
typedef __bf16 bf16x4v __attribute__((ext_vector_type(4)));
typedef float f32x4 __attribute__((ext_vector_type(4)));

#define S_LEN 2048
#define DMODEL 512
// log2(e)/sqrt(512): Q pre-scale so softmax exp is a bare exp2
#define QSCALE 0.06375870914f

#define GLDS(g, l) __builtin_amdgcn_global_load_lds(                  \
    (const __attribute__((address_space(1))) void*)(g),               \
    (__attribute__((address_space(3))) void*)(l), 16, 0, 0)

#define EXP2(x) __builtin_amdgcn_exp2f(x)

// One launch: embed (1,048,576 f4) then Wq,Wk,Wv,Wo (65,536 f4 each).
__global__ __launch_bounds__(256) void cast_all(
    const float* __restrict__ embed, const float* __restrict__ Wq,
    const float* __restrict__ Wk, const float* __restrict__ Wv,
    const float* __restrict__ Wo,
    bf16* __restrict__ Eb, bf16* __restrict__ Wqkv, bf16* __restrict__ Wob) {
  int i = blockIdx.x * 256 + threadIdx.x;
  const float* src;
  bf16* dst;
  int il;
  if (i < 1048576) {
    src = embed; dst = Eb; il = i;
  } else {
    int j = i - 1048576;
    int w = j >> 16;
    il = j & 65535;
    src = (w == 0) ? Wq : (w == 1) ? Wk : (w == 2) ? Wv : Wo;
    dst = (w == 3) ? Wob : Wqkv + (size_t)w * 262144;
  }
  float4 v = reinterpret_cast<const float4*>(src)[il];
  bf16x4v o;
  o[0] = (bf16)v.x; o[1] = (bf16)v.y; o[2] = (bf16)v.z; o[3] = (bf16)v.w;
  *reinterpret_cast<bf16x4v*>(dst + (size_t)il * 4) = o;
}

// ---- 128x128 tile GEMM core: C = A[M,512] * Bw[N,512]^T, K=512, BK=64 ----
__device__ __forceinline__ void gemm128_core(
    const bf16* __restrict__ A, const bf16* __restrict__ Bw,
    int row0, int col0, bf16* As, bf16* Bs, f32x4 (&acc)[4][4]) {
  int tid = threadIdx.x;
  int w = tid >> 6, l = tid & 63, lr = l & 15, lg = l >> 4;
  int wr = w >> 1, wc = w & 1;

  int srow = w * 8 + (l >> 3);
  int scol = ((l & 7) ^ (srow & 7)) << 3;
  const bf16* ga = A + (size_t)(row0 + srow) * DMODEL + scol;
  const bf16* gb = Bw + (size_t)(col0 + srow) * DMODEL + scol;
  char* asb = (char*)As;
  char* bsb = (char*)Bs;
  int sbase = w * 1024;

  int aoff[4], boff[4];
#pragma unroll
  for (int m = 0; m < 4; ++m) {
    aoff[m] = (wr * 64 + m * 16 + lr) * 128 + (((lg ^ (lr & 7))) << 4);
    boff[m] = (wc * 64 + m * 16 + lr) * 128 + (((lg ^ (lr & 7))) << 4);
  }

  for (int k0 = 0; k0 < DMODEL; k0 += 64) {
#pragma unroll
    for (int qt = 0; qt < 4; ++qt) {
      GLDS(ga + (size_t)qt * 32 * DMODEL, asb + qt * 4096 + sbase);
      GLDS(gb + (size_t)qt * 32 * DMODEL, bsb + qt * 4096 + sbase);
    }
    ga += 64; gb += 64;
    __syncthreads();

    bf16x8 af[2][4], bfv[2][4];
#pragma unroll
    for (int m = 0; m < 4; ++m) {
      af[0][m] = *(const bf16x8*)(asb + aoff[m]);
      af[1][m] = *(const bf16x8*)(asb + (aoff[m] ^ 0x40));
      bfv[0][m] = *(const bf16x8*)(bsb + boff[m]);
      bfv[1][m] = *(const bf16x8*)(bsb + (boff[m] ^ 0x40));
    }
#pragma unroll
    for (int m = 0; m < 4; ++m)
#pragma unroll
      for (int n = 0; n < 4; ++n) {
        acc[m][n] = __builtin_amdgcn_mfma_f32_16x16x32_bf16(af[0][m], bfv[0][n], acc[m][n], 0, 0, 0);
        acc[m][n] = __builtin_amdgcn_mfma_f32_16x16x32_bf16(af[1][m], bfv[1][n], acc[m][n], 0, 0, 0);
      }
    __syncthreads();
  }
}

// Fused QKV GEMM: Wqkv[1536][512]; col-tiles 0-3 = Q, 4-7 = K, 8-11 = V.
__global__ __launch_bounds__(256) void gemm_qkv(
    const bf16* __restrict__ A, const bf16* __restrict__ Wqkv,
    const float* __restrict__ bq, const float* __restrict__ bk, const float* __restrict__ bv,
    bf16* __restrict__ Qb, bf16* __restrict__ Kb, bf16* __restrict__ Vt) {
  __shared__ __align__(16) bf16 As[128 * 64];
  __shared__ __align__(16) bf16 Bs[128 * 64];
  int row0 = blockIdx.x * 128, col0 = blockIdx.y * 128;
  f32x4 acc[4][4] = {};
  gemm128_core(A, Wqkv, row0, col0, As, Bs, acc);

  int tid = threadIdx.x;
  int w = tid >> 6, l = tid & 63, lr = l & 15, lg = l >> 4;
  int wr = w >> 1, wc = w & 1;
  int z2 = col0 >> 9;  // 0=Q 1=K 2=V (uniform per block)
  if (z2 < 2) {
    bf16* O = z2 ? Kb : Qb;
    const float* bias = z2 ? bk : bq;
    float qs = z2 ? 1.0f : QSCALE;
#pragma unroll
    for (int n = 0; n < 4; ++n) {
      int cg = (col0 & 511) + wc * 64 + n * 16 + lr;
      float bi = bias[cg];
#pragma unroll
      for (int m = 0; m < 4; ++m) {
        int rg = row0 + wr * 64 + m * 16 + lg * 4;
#pragma unroll
        for (int r = 0; r < 4; ++r)
          O[(size_t)(rg + r) * DMODEL + cg] = (bf16)((acc[m][n][r] + bi) * qs);
      }
    }
  } else {
    // V: store transposed Vt[b][h][e][s]
#pragma unroll
    for (int n = 0; n < 4; ++n) {
      int ep = (col0 & 511) + wc * 64 + n * 16 + lr;
      int h = ep >> 6, e = ep & 63;
      float bi = bv[ep];
#pragma unroll
      for (int m = 0; m < 4; ++m) {
        int rg = row0 + wr * 64 + m * 16 + lg * 4;
        int b = rg >> 11, s0 = rg & 2047;
        bf16x4v pk;
#pragma unroll
        for (int r = 0; r < 4; ++r) pk[r] = (bf16)(acc[m][n][r] + bi);
        *(bf16x4v*)(Vt + ((size_t)((b * 8 + h) * 64 + e)) * S_LEN + s0) = pk;
      }
    }
  }
}

// Wo GEMM + bias + residual, bf16 out (LN reads bf16).
__global__ __launch_bounds__(256) void gemm_wo(
    const bf16* __restrict__ A, const bf16* __restrict__ W,
    const float* __restrict__ bo, const float* __restrict__ embed,
    bf16* __restrict__ X) {
  __shared__ __align__(16) bf16 As[128 * 64];
  __shared__ __align__(16) bf16 Bs[128 * 64];
  int row0 = blockIdx.x * 128, col0 = blockIdx.y * 128;
  f32x4 acc[4][4] = {};
  gemm128_core(A, W, row0, col0, As, Bs, acc);

  int tid = threadIdx.x;
  int w = tid >> 6, l = tid & 63, lr = l & 15, lg = l >> 4;
  int wr = w >> 1, wc = w & 1;
#pragma unroll
  for (int n = 0; n < 4; ++n) {
    int cg = col0 + wc * 64 + n * 16 + lr;
    float bi = bo[cg];
#pragma unroll
    for (int m = 0; m < 4; ++m) {
      int rg = row0 + wr * 64 + m * 16 + lg * 4;
#pragma unroll
      for (int r = 0; r < 4; ++r)
        X[(size_t)(rg + r) * DMODEL + cg] =
            (bf16)(acc[m][n][r] + bi + embed[(size_t)(rg + r) * DMODEL + cg]);
    }
  }
}

// SUF[bh][j][e] = sum_{t >= 16j} V[t][e], j = 0..128 (SUF[128]=0).
// 256 blocks: (bh, e-group of 8); 256 thr = (el 0..7, seg 0..31), 4 chunks/seg.
__global__ __launch_bounds__(256) void suf_kernel(const bf16* __restrict__ Vt,
                                                  float* __restrict__ SUF) {
  int bh = blockIdx.x >> 3;
  int eg = blockIdx.x & 7;
  int el = threadIdx.x & 7;
  int seg = threadIdx.x >> 3;  // 0..31
  int e = eg * 8 + el;
  __shared__ float segtot[32][9];
  const bf16* vrow = Vt + ((size_t)bh * 64 + e) * S_LEN;
  float loc[4];
  float carry = 0.f;
#pragma unroll
  for (int j = 3; j >= 0; --j) {
    int jj = seg * 4 + j;
    bf16x8 a = *(const bf16x8*)(vrow + jj * 16);
    bf16x8 b2 = *(const bf16x8*)(vrow + jj * 16 + 8);
    float s = 0.f;
#pragma unroll
    for (int k = 0; k < 8; ++k) s += (float)a[k] + (float)b2[k];
    carry += s;
    loc[j] = carry;
  }
  segtot[seg][el] = carry;
  __syncthreads();
  float add = 0.f;
  for (int s2 = seg + 1; s2 < 32; ++s2) add += segtot[s2][el];
  float* srow = SUF + (size_t)bh * 129 * 64 + e;
#pragma unroll
  for (int j = 0; j < 4; ++j) srow[(size_t)(seg * 4 + j) * 64] = loc[j] + add;
  if (seg == 0) srow[(size_t)128 * 64] = 0.f;
}

// Flash attention v11: XCD-aware 1D grid (512 blocks): XCD g owns bh {4g..4g+3},
// 16 p each, biggest-p first. 8 waves: 0-3 big tile (16+p), 4-7 small (15-p);
// KVBLK=128 per barrier, two wave-local phases; flat softmax via raw v_exp_f32.
__global__ __launch_bounds__(512) void flash_attn(
    const bf16* __restrict__ Qb, const bf16* __restrict__ Kb,
    const bf16* __restrict__ Vt, const float* __restrict__ SUF,
    bf16* __restrict__ attO) {
  int id = blockIdx.x;           // 0..511
  int g = id & 7;                // XCD (dispatch round-robins id%8)
  int j = id >> 3;               // 0..63
  int bh = g * 4 + (j & 3);      // 4 bh per XCD
  int p = 15 - (j >> 2);         // biggest-first within each XCD
  int b = bh >> 3, h = bh & 7;
  int tid = threadIdx.x;
  int w = tid >> 6, l = tid & 63, lr = l & 15, lg = l >> 4;
  int wsub = w & 3;
  int qtile = (w < 4) ? (16 + p) : (15 - p);
  int qb = qtile * 64;
  int qbw = qb + 16 * wsub;          // first q-row of this wave's strip
  int tmax_w = qbw + 16;             // analytic tail starts here
  int nt = (18 + p) >> 1;            // block-uniform 128-wide KV tiles
  int ntw = (tmax_w + 127) >> 7;     // this wave's active iterations

  __shared__ __align__(16) bf16 kl[2][128 * 64];    // K tile [t][e], swizzled
  __shared__ __align__(16) bf16 vl[2][2][64 * 64];  // V^T subtiles [e][t], swizzled
  __shared__ __align__(16) bf16 pl[8][16 * 64];     // per-wave P tile [s][t], swizzled

  const bf16* qptr = Qb + ((size_t)(b * S_LEN) + qbw + lr) * DMODEL + h * 64 + lg * 8;
  bf16x8 aq0 = *(const bf16x8*)(qptr);
  bf16x8 aq1 = *(const bf16x8*)(qptr + 32);

  float lsum[4] = {0.f, 0.f, 0.f, 0.f};
  f32x4 acc[4] = {};

  int grow = tid >> 3, gch = tid & 7;
  int sch = ((gch ^ (grow & 7)) << 3);   // (grow+64)&7 == grow&7
  const bf16* Kg = Kb + ((size_t)(b * S_LEN) + grow) * DMODEL + h * 64 + sch;
  const bf16* Vg = Vt + ((size_t)(bh * 64) + grow) * S_LEN + sch;
  int sdst = w * 1024;  // wave-uniform LDS dest (lane*16 implicit)

  int sw0 = (lg ^ (lr & 7)) << 4;
  int sw4 = sw0 ^ 0x40;
  char* plb = (char*)pl[w];

  // prologue: stage tile 0 (K rows 0-63, 64-127; V subtiles 0,1)
  GLDS(Kg, (char*)kl[0] + sdst);
  GLDS(Kg + (size_t)64 * DMODEL, (char*)kl[0] + 8192 + sdst);
  GLDS(Vg, (char*)vl[0][0] + sdst);
  GLDS(Vg + 64, (char*)vl[0][1] + sdst);
  asm volatile("s_waitcnt vmcnt(0)" ::: "memory");
  __syncthreads();

  int cur = 0;
  for (int it = 0; it < nt; ++it) {
    int t0 = it << 7;
    if (it + 1 < nt) {
      GLDS(Kg + (size_t)(t0 + 128) * DMODEL, (char*)kl[cur ^ 1] + sdst);
      GLDS(Kg + (size_t)(t0 + 192) * DMODEL, (char*)kl[cur ^ 1] + 8192 + sdst);
      GLDS(Vg + (t0 + 128), (char*)vl[cur ^ 1][0] + sdst);
      GLDS(Vg + (t0 + 192), (char*)vl[cur ^ 1][1] + sdst);
    }
    if (it < ntw) {  // wave-uniform skip of fully-masked tiles
      char* klb = (char*)kl[cur];
      bool ph1 = (t0 + 64) < tmax_w;  // wave-uniform

      // QK^T over the 128-t tile (sf[c] covers t = t0+16c+lr)
      f32x4 sf[8];
      const f32x4 fz = {0.f, 0.f, 0.f, 0.f};
      int ncq = ph1 ? 8 : 4;
      __builtin_amdgcn_s_setprio(1);
#pragma unroll 8
      for (int c = 0; c < 8; ++c) {
        if (c < ncq) {
          int rb = (16 * c + lr) * 128;
          bf16x8 bk0 = *(const bf16x8*)(klb + rb + sw0);
          bf16x8 bk1 = *(const bf16x8*)(klb + rb + sw4);
          f32x4 t = __builtin_amdgcn_mfma_f32_16x16x32_bf16(aq0, bk0, fz, 0, 0, 0);
          sf[c] = __builtin_amdgcn_mfma_f32_16x16x32_bf16(aq1, bk1, t, 0, 0, 0);
        }
      }
      __builtin_amdgcn_s_setprio(0);

      // two phases: softmax (c-half) -> P tile -> PV with V subtile
#pragma unroll
      for (int hp = 0; hp < 2; ++hp) {
        int t0p = t0 + 64 * hp;
        if (hp == 1 && !ph1) break;
        char* vlb = (char*)vl[cur][hp];

        if (t0p + 64 <= qbw) {
          // interior: no masking
#pragma unroll
          for (int r = 0; r < 4; ++r) {
            int row = lg * 4 + r;
            int pbase = row * 128 + ((lr & 7) << 1);
            int xorv = row & 7;
            float psum = 0.f;
#pragma unroll
            for (int c = 0; c < 4; ++c) {
              float pv = EXP2(sf[4 * hp + c][r]);
              psum += pv;
              int chunk = 2 * c + (lr >> 3);
              *(bf16*)(plb + pbase + (((chunk ^ xorv) << 4))) = (bf16)pv;
            }
            lsum[r] += psum;
          }
        } else {
          // boundary: per-element mask (x=0 in tril-zero region, -inf past tail)
#pragma unroll
          for (int r = 0; r < 4; ++r) {
            int sg = qbw + lg * 4 + r;
            int row = lg * 4 + r;
            int pbase = row * 128 + ((lr & 7) << 1);
            int xorv = row & 7;
            float psum = 0.f;
#pragma unroll
            for (int c = 0; c < 4; ++c) {
              int tg = t0p + 16 * c + lr;
              float x = (tg <= sg) ? sf[4 * hp + c][r] : ((tg < tmax_w) ? 0.f : -1e30f);
              float pv = EXP2(x);
              psum += pv;
              int chunk = 2 * c + (lr >> 3);
              *(bf16*)(plb + pbase + (((chunk ^ xorv) << 4))) = (bf16)pv;
            }
            lsum[r] += psum;
          }
        }

        bf16x8 pa0 = *(const bf16x8*)(plb + lr * 128 + sw0);
        bf16x8 pa1 = *(const bf16x8*)(plb + lr * 128 + sw4);
        __builtin_amdgcn_s_setprio(1);
#pragma unroll
        for (int c = 0; c < 4; ++c) {
          int rb = (16 * c + lr) * 128;
          bf16x8 bv0 = *(const bf16x8*)(vlb + rb + sw0);
          bf16x8 bv1 = *(const bf16x8*)(vlb + rb + sw4);
          acc[c] = __builtin_amdgcn_mfma_f32_16x16x32_bf16(pa0, bv0, acc[c], 0, 0, 0);
          acc[c] = __builtin_amdgcn_mfma_f32_16x16x32_bf16(pa1, bv1, acc[c], 0, 0, 0);
        }
        __builtin_amdgcn_s_setprio(0);
      }
    }
    asm volatile("s_waitcnt vmcnt(0)" ::: "memory");
    __syncthreads();
    cur ^= 1;
  }

#pragma unroll
  for (int r = 0; r < 4; ++r) {
#pragma unroll
    for (int d = 1; d < 16; d <<= 1) lsum[r] += __shfl_xor(lsum[r], d, 64);
  }

  int j16 = tmax_w >> 4;
  const float* suf = SUF + ((size_t)bh * 129 + j16) * 64;
  float cnt = (float)(S_LEN - tmax_w);
  float sufe[4];
#pragma unroll
  for (int c = 0; c < 4; ++c) sufe[c] = suf[16 * c + lr];
#pragma unroll
  for (int r = 0; r < 4; ++r) {
    float inv = 1.f / (lsum[r] + cnt);
    int sg = qbw + lg * 4 + r;
#pragma unroll
    for (int c = 0; c < 4; ++c) {
      float o = (acc[c][r] + sufe[c]) * inv;
      attO[((size_t)(b * S_LEN) + sg) * DMODEL + h * 64 + 16 * c + lr] = (bf16)o;
    }
  }
}

__global__ __launch_bounds__(256) void ln_kernel(const bf16* __restrict__ x,
                                                 const float* __restrict__ gamma,
                                                 const float* __restrict__ beta,
                                                 float* __restrict__ out) {
  int row = blockIdx.x * 4 + (threadIdx.x >> 6);
  int l = threadIdx.x & 63;
  bf16x8 xv = *(const bf16x8*)(x + (size_t)row * DMODEL + l * 8);
  float xf[8];
  float s = 0.f, s2 = 0.f;
#pragma unroll
  for (int k = 0; k < 8; ++k) {
    xf[k] = (float)xv[k];
    s += xf[k];
    s2 += xf[k] * xf[k];
  }
#pragma unroll
  for (int d = 1; d < 64; d <<= 1) {
    s += __shfl_xor(s, d, 64);
    s2 += __shfl_xor(s2, d, 64);
  }
  float mean = s * (1.f / 512.f);
  float var = s2 * (1.f / 512.f) - mean * mean;
  float rstd = rsqrtf(var + 1e-5f);
  const float4* g4 = reinterpret_cast<const float4*>(gamma) + l * 2;
  const float4* b4 = reinterpret_cast<const float4*>(beta) + l * 2;
  float4 g0 = g4[0], g1 = g4[1], bb0 = b4[0], bb1 = b4[1];
  float4 o0, o1;
  o0.x = (xf[0] - mean) * rstd * g0.x + bb0.x;
  o0.y = (xf[1] - mean) * rstd * g0.y + bb0.y;
  o0.z = (xf[2] - mean) * rstd * g0.z + bb0.z;
  o0.w = (xf[3] - mean) * rstd * g0.w + bb0.w;
  o1.x = (xf[4] - mean) * rstd * g1.x + bb1.x;
  o1.y = (xf[5] - mean) * rstd * g1.y + bb1.y;
  o1.z = (xf[6] - mean) * rstd * g1.z + bb1.z;
  o1.w = (xf[7] - mean) * rstd * g1.w + bb1.w;
  float4* orow = reinterpret_cast<float4*>(out + (size_t)row * DMODEL) + l * 2;
  orow[0] = o0;
  orow[1] = o1;
}

extern "C" void kernel_launch(void* const* d_in, const int* in_sizes, int n_in,
                              void* d_out, int out_size, void* d_ws, size_t ws_size,
                              hipStream_t stream) {
  const float* embed = (const float*)d_in[0];
  const float* Wq = (const float*)d_in[1];
  const float* bq = (const float*)d_in[2];
  const float* Wk = (const float*)d_in[3];
  const float* bk = (const float*)d_in[4];
  const float* Wv = (const float*)d_in[5];
  const float* bv = (const float*)d_in[6];
  const float* Wo = (const float*)d_in[7];
  const float* bo = (const float*)d_in[8];
  const float* gamma = (const float*)d_in[9];
  const float* beta = (const float*)d_in[10];
  float* out = (float*)d_out;

  char* ws = (char*)d_ws;
  size_t off = 0;
  auto alc = [&](size_t b) { size_t o = off; off += (b + 255) & ~(size_t)255; return o; };
  bf16* Eb    = (bf16*)(ws + alc(8192ull * 512 * 2));
  bf16* Wqkv  = (bf16*)(ws + alc(1536ull * 512 * 2));
  bf16* Wob   = (bf16*)(ws + alc(512ull * 512 * 2));
  bf16* Qb    = (bf16*)(ws + alc(8192ull * 512 * 2));
  bf16* Kb    = (bf16*)(ws + alc(8192ull * 512 * 2));
  bf16* Vt    = (bf16*)(ws + alc(8192ull * 512 * 2));
  float* SUF  = (float*)(ws + alc(32ull * 129 * 64 * 4));
  bf16* AttO  = (bf16*)(ws + alc(8192ull * 512 * 2));
  bf16* Xb    = (bf16*)(ws + alc(8192ull * 512 * 2));
  (void)ws_size; (void)n_in; (void)in_sizes; (void)out_size;

  cast_all<<<5120, 256, 0, stream>>>(embed, Wq, Wk, Wv, Wo, Eb, Wqkv, Wob);

  gemm_qkv<<<dim3(64, 12), 256, 0, stream>>>(Eb, Wqkv, bq, bk, bv, Qb, Kb, Vt);
  suf_kernel<<<256, 256, 0, stream>>>(Vt, SUF);
  flash_attn<<<512, 512, 0, stream>>>(Qb, Kb, Vt, SUF, AttO);
  gemm_wo<<<dim3(64, 4), 256, 0, stream>>>(AttO, Wob, bo, embed, Xb);
  ln_kernel<<<2048, 256, 0, stream>>>(Xb, gamma, beta, out);
}